// Round 1
// baseline (3268.648 us; speedup 1.0000x reference)
//
#include <hip/hip_runtime.h>
#include <hip/hip_fp16.h>

// Unidir_LSTM: h_t = sig(o)*tanh(sig(i)*tanh(g)); f-gate dead (cell carry always 0).
// R6: recur step was 5.2us vs ~2us modeled. Two structural drags found in counters:
//  (1) Xp acc-preload = 12 scattered scalar HBM loads (~900cy) BLOCKING before the
//      poll each step (Xp 201MB streamed, never cached; FETCH_SIZE ~= Xp).
//  (2) LDS staging round-trip after the poll: gload_lds 32KB + 2 barriers + 64KB
//      ds_read w/ 352 conflict-cy/block-step (SQ_LDS_BANK_CONFLICT 2.3e7).
// Fix: fuse input GEMM into the recurrence (Wi3 frags register-resident, X slab
// MFMA'd per step -> xp_gemm kernel + 360MB Xp HBM traffic deleted; X loads issued
// pre-poll so L2/L3 latency hides under the wait), and load h A-frags straight
// global->VGPR. Waves = 4 disjoint K-quarters (no A duplication; 48KB unique L2
// reads/block/step), reduce via padded gbuf (stride-20 rows = 2-way banks = free),
// epilogue split over all 4 waves (2 h-vals/thread), per-wave flag after own
// vmcnt(0) drain. 2 barriers/step instead of 4.
// Predict: recur 1335 -> ~700-900us, FETCH 157->~45MB, BANK_CONFLICT 2.3e7 -> ~0,
// WRITE ~68MB unchanged, total 1607 -> ~950-1150us.

typedef __fp16 f16x8 __attribute__((ext_vector_type(8)));
typedef __fp16 f16x4 __attribute__((ext_vector_type(4)));
typedef float  f32x4 __attribute__((ext_vector_type(4)));

#define MFMA16(a, b, c) __builtin_amdgcn_mfma_f32_16x16x32_f16(a, b, c, 0, 0, 0)

__device__ __forceinline__ float sigmoid_f(float x) {
  return 1.f / (1.f + __expf(-x));
}
__device__ __forceinline__ float tanh_f(float x) {
  x = fminf(fmaxf(x, -15.f), 15.f);
  float e = __expf(2.f * x);
  return (e - 1.f) / (e + 1.f);
}

static constexpr int SS = 256;

// ---------------- prep: pack W_ih/W_hh rows {i,g,o} to fp16, bias3 = b_ih+b_hh ----
__global__ void prep_kernel(const float* __restrict__ W_ih, const float* __restrict__ W_hh,
                            const float* __restrict__ b_ih, const float* __restrict__ b_hh,
                            __fp16* __restrict__ Wi3, __fp16* __restrict__ Wh3,
                            float* __restrict__ bias3) {
  int j3 = blockIdx.x;                 // 0..3071 packed row
  int g = j3 >> 10, j = j3 & 1023;
  int orig = (g == 0 ? 0 : (g == 1 ? 2048 : 3072)) + j;  // i,g,o rows of 4H
  int tid = threadIdx.x;
  {
    float4 v = *(const float4*)(W_hh + (size_t)orig * 1024 + tid * 4);
    f16x4 o = {(__fp16)v.x, (__fp16)v.y, (__fp16)v.z, (__fp16)v.w};
    *(f16x4*)(Wh3 + (size_t)j3 * 1024 + tid * 4) = o;
  }
  if (tid < 128) {
    float4 v = *(const float4*)(W_ih + (size_t)orig * 512 + tid * 4);
    f16x4 o = {(__fp16)v.x, (__fp16)v.y, (__fp16)v.z, (__fp16)v.w};
    *(f16x4*)(Wi3 + (size_t)j3 * 512 + tid * 4) = o;
  }
  if (tid == 0) bias3[j3] = b_ih[orig] + b_hh[orig];
}

// ---------------- gather: X[t*128+b][e] = fp16(embed[tok[b][t]][e]) ----------------
__global__ void gather_kernel(const int* __restrict__ tok, const float* __restrict__ emb,
                              __fp16* __restrict__ X) {
  int m = blockIdx.x;                  // 0..32767 = t*128 + b
  int t = m >> 7, b = m & 127;
  int tk = tok[b * SS + t];            // inputs is [B][S]
  int e0 = threadIdx.x * 8;
  const float* src = emb + (size_t)tk * 512 + e0;
  float4 v0 = *(const float4*)src;
  float4 v1 = *(const float4*)(src + 4);
  f16x8 o;
  o[0] = (__fp16)v0.x; o[1] = (__fp16)v0.y; o[2] = (__fp16)v0.z; o[3] = (__fp16)v0.w;
  o[4] = (__fp16)v1.x; o[5] = (__fp16)v1.y; o[6] = (__fp16)v1.z; o[7] = (__fp16)v1.w;
  *(f16x8*)(X + (size_t)m * 512 + e0) = o;
}

// ---------------- recurrence: persistent, fused input GEMM, direct-reg A loads ----
// 256 blocks = (bg 0..7: 16 batch rows, pinned to XCD bg via bid&7) x (n 0..31:
// 32 h-cols). 4 waves = 4 disjoint K-quarters (h: 256 K each; X: 128 K each) over
// the same 32 cols -> no duplicated A loads. Per wave register-resident B-frags:
// Wh 3g x 2ct x 8kk (192 VGPR) + Wi 3g x 2ct x 4kk (96 VGPR). Per step: issue X
// A-frags (L2/L3), poll 128 group flags (relaxed, agent), acquire fence, issue h
// A-frags (global->VGPR from the XCD-shared L2), 24 X-MFMAs + 48 h-MFMAs, 4-way
// K-reduce via gbuf (2 barriers), epilogue split over all 4 waves (wave w owns
// ctile w&1, row-half w>>1 -> 2 h-values/thread), per-wave flag store after own
// s_waitcnt vmcnt(0) (stores ack'd in XCD L2; same-XCD consumers see them).
__global__ __launch_bounds__(256, 1) void recur_kernel(const __fp16* __restrict__ Wh3,
                                                       const __fp16* __restrict__ Wi3,
                                                       const __fp16* __restrict__ X,
                                                       const float* __restrict__ bias3,
                                                       __fp16* __restrict__ hbuf,
                                                       int* __restrict__ flags,
                                                       float* __restrict__ out) {
  const int bid = blockIdx.x;
  const int bg = bid & 7, n = bid >> 3;   // XCD-local batch groups
  const int b0 = bg * 16, j0 = n * 32;
  const int tid = threadIdx.x, wid = tid >> 6, lane = tid & 63;
  const int l15 = lane & 15, quad = lane >> 4;
  const int kq = wid;                     // this wave's K-quarter
  const int ct_e = wid & 1, rh = wid >> 1;  // epilogue ownership: col-tile, row-half

  // [wave][gate][ctile][row][col+pad]; stride 20 floats -> 2-way banks (free, m136)
  __shared__ float gbuf[4][3][2][16][20];

  // persistent B fragments (col = j0 + ct*16 + l15, k = quarter + kk*32 + quad*8)
  f16x8 wh[3][2][8];
  f16x8 wi[3][2][4];
#pragma unroll
  for (int g = 0; g < 3; ++g)
#pragma unroll
    for (int ct = 0; ct < 2; ++ct) {
      const __fp16* wr = Wh3 + (size_t)(g * 1024 + j0 + ct * 16 + l15) * 1024 + kq * 256 + quad * 8;
#pragma unroll
      for (int kk = 0; kk < 8; ++kk) wh[g][ct][kk] = *(const f16x8*)(wr + kk * 32);
      const __fp16* wr2 = Wi3 + (size_t)(g * 1024 + j0 + ct * 16 + l15) * 512 + kq * 128 + quad * 8;
#pragma unroll
      for (int kk = 0; kk < 4; ++kk) wi[g][ct][kk] = *(const f16x8*)(wr2 + kk * 32);
    }

  float bs[3];
#pragma unroll
  for (int g = 0; g < 3; ++g) bs[g] = bias3[g * 1024 + j0 + ct_e * 16 + l15];

  const __fp16* xrow = X + (size_t)(b0 + l15) * 512 + kq * 128 + quad * 8;
  const __fp16* hrow = hbuf + (size_t)(b0 + l15) * 1024 + kq * 256 + quad * 8;
  int* myflag = flags + bg * 128 + n * 4 + wid;
  int* pollp = flags + bg * 128 + lane;

  for (int t = 0; t < SS; ++t) {
    // (a) X A-frags: no h dependency -> issue before the poll, latency hides under it
    f16x8 xa[4];
    {
      const __fp16* xp = xrow + (size_t)t * 65536;
#pragma unroll
      for (int kk = 0; kk < 4; ++kk) xa[kk] = *(const f16x8*)(xp + kk * 32);
    }
    // (b) wait for all 128 producer-waves of our batch group (relaxed polls, one
    //     acquire fence once satisfied — invalidates L1 before the h reads)
    if (t > 0) {
      for (;;) {
        int v0 = __hip_atomic_load(pollp, __ATOMIC_RELAXED, __HIP_MEMORY_SCOPE_AGENT);
        int v1 = __hip_atomic_load(pollp + 64, __ATOMIC_RELAXED, __HIP_MEMORY_SCOPE_AGENT);
        if (__ballot((v0 < t) || (v1 < t)) == 0ull) break;
        __builtin_amdgcn_s_sleep(1);
      }
      __builtin_amdgcn_fence(__ATOMIC_ACQUIRE, "agent");
    }
    // (c) h A-frags straight global->VGPR (XCD L2 hit); issue before X-MFMA so the
    //     24 X MFMAs cover part of the load latency
    f16x8 ha[8];
    {
      const __fp16* hp = hrow + (size_t)t * 131072;
#pragma unroll
      for (int kk = 0; kk < 8; ++kk) ha[kk] = *(const f16x8*)(hp + kk * 32);
    }
    // (d) MFMA: acc starts with the fused input-GEMM contribution
    f32x4 acc[3][2];
#pragma unroll
    for (int g = 0; g < 3; ++g)
#pragma unroll
      for (int ct = 0; ct < 2; ++ct) {
        f32x4 z = {0.f, 0.f, 0.f, 0.f};
        acc[g][ct] = z;
      }
#pragma unroll
    for (int kk = 0; kk < 4; ++kk)
#pragma unroll
      for (int g = 0; g < 3; ++g)
#pragma unroll
        for (int ct = 0; ct < 2; ++ct)
          acc[g][ct] = MFMA16(xa[kk], wi[g][ct][kk], acc[g][ct]);
#pragma unroll
    for (int kk = 0; kk < 8; ++kk)
#pragma unroll
      for (int g = 0; g < 3; ++g)
#pragma unroll
        for (int ct = 0; ct < 2; ++ct)
          acc[g][ct] = MFMA16(ha[kk], wh[g][ct][kk], acc[g][ct]);
    // (e) 4-way K reduction via gbuf
#pragma unroll
    for (int g = 0; g < 3; ++g)
#pragma unroll
      for (int ct = 0; ct < 2; ++ct)
#pragma unroll
        for (int r = 0; r < 4; ++r)
          gbuf[kq][g][ct][quad * 4 + r][l15] = acc[g][ct][r];
    __syncthreads();
    float sum[3][2];
#pragma unroll
    for (int g = 0; g < 3; ++g)
#pragma unroll
      for (int rr = 0; rr < 2; ++rr) {
        const int r = rh * 2 + rr;
        sum[g][rr] = gbuf[0][g][ct_e][quad * 4 + r][l15] + gbuf[1][g][ct_e][quad * 4 + r][l15] +
                     gbuf[2][g][ct_e][quad * 4 + r][l15] + gbuf[3][g][ct_e][quad * 4 + r][l15];
      }
    __syncthreads();  // gbuf free for next step's partials
    // (f) epilogue: 2 h-values per thread, all 4 waves participate
#pragma unroll
    for (int rr = 0; rr < 2; ++rr) {
      const int r = rh * 2 + rr;
      float gi = sum[0][rr] + bs[0];
      float gg = sum[1][rr] + bs[1];
      float go = sum[2][rr] + bs[2];
      float cv = sigmoid_f(gi) * tanh_f(gg);
      float hN = sigmoid_f(go) * tanh_f(cv);
      const int row = b0 + quad * 4 + r;
      const int col = j0 + ct_e * 16 + l15;
      if (t == SS - 1) out[(size_t)row * 1024 + col] = hN;
      else hbuf[(size_t)(t + 1) * 131072 + (size_t)row * 1024 + col] = (__fp16)hN;
    }
    // (g) per-wave release: drain own stores (ack'd in XCD L2), then relaxed flag
    if (t < SS - 1) {
      asm volatile("s_waitcnt vmcnt(0)" ::: "memory");
      if (lane == 0)
        __hip_atomic_store(myflag, t + 1, __ATOMIC_RELAXED, __HIP_MEMORY_SCOPE_AGENT);
    }
  }
}

extern "C" void kernel_launch(void* const* d_in, const int* in_sizes, int n_in,
                              void* d_out, int out_size, void* d_ws, size_t ws_size,
                              hipStream_t stream) {
  const int*   tok  = (const int*)d_in[0];
  const float* emb  = (const float*)d_in[1];
  const float* W_ih = (const float*)d_in[2];
  const float* W_hh = (const float*)d_in[3];
  const float* b_ih = (const float*)d_in[4];
  const float* b_hh = (const float*)d_in[5];
  float* out = (float*)d_out;
  char* ws = (char*)d_ws;

  // ws layout (bytes), total 110,116,864 (~105 MB)
  __fp16* X     = (__fp16*)(ws + 0);              // 33,554,432
  __fp16* Wi3   = (__fp16*)(ws + 33554432);       //  3,145,728
  __fp16* Wh3   = (__fp16*)(ws + 36700160);       //  6,291,456
  float*  bias3 = (float*) (ws + 42991616);       //     12,288
  int*    flags = (int*)   (ws + 43003904);       //      4,096 (1024 flags, 4B packed)
  __fp16* hbuf  = (__fp16*)(ws + 43008000);       // 67,108,864 (256 step buffers)

  (void)hipMemsetAsync(flags, 0, 4096, stream);
  (void)hipMemsetAsync(hbuf, 0, 131072 * 2, stream);  // h_0 = 0

  prep_kernel<<<3072, 256, 0, stream>>>(W_ih, W_hh, b_ih, b_hh, Wi3, Wh3, bias3);
  gather_kernel<<<32768, 64, 0, stream>>>(tok, emb, X);
  recur_kernel<<<256, 256, 0, stream>>>(Wh3, Wi3, X, bias3, hbuf, flags, out);
}

// Round 2
// 1326.794 us; speedup vs baseline: 2.4636x; 2.4636x over previous
//
#include <hip/hip_runtime.h>
#include <hip/hip_fp16.h>

// Unidir_LSTM: h_t = sig(o)*tanh(sig(i)*tanh(g)); f-gate dead (cell carry always 0).
// R7: R6 (fused input GEMM, direct-reg A loads) regressed 1335->3130us. Post-mortem:
//   the per-WAVE agent acquire fence compiles to buffer_inv invalidating L1+L2
//   (agent coherence point is behind the non-coherent XCD L2s). 128 invalidates
//   per XCD per step nuked the h/X lines (FETCH 88MB = X 33 + h re-fetch) and
//   serialized ~10us/step. The fence is removable: consumer L1 can never hold a
//   stale hbuf line (fresh per-step ring address, L1 write-through/no-allocate),
//   producer orders h-stores -> vmcnt(0) (L2 ack) -> flag (MALL), wave is in-order.
//   Replace fence with a compiler-only barrier. Also revert to R5's proven flag
//   layout: one flag per block, 64B apart (R6's packed per-wave flags put 128
//   writes on 8 shared MALL lines).
// Predict: recur 3130 -> ~700-950us, FETCH 88 -> ~40MB (h L2-hits), WRITE ~70MB
//   unchanged, MfmaUtil ~12-15%, conflicts stay 0.

typedef __fp16 f16x8 __attribute__((ext_vector_type(8)));
typedef __fp16 f16x4 __attribute__((ext_vector_type(4)));
typedef float  f32x4 __attribute__((ext_vector_type(4)));

#define MFMA16(a, b, c) __builtin_amdgcn_mfma_f32_16x16x32_f16(a, b, c, 0, 0, 0)

__device__ __forceinline__ float sigmoid_f(float x) {
  return 1.f / (1.f + __expf(-x));
}
__device__ __forceinline__ float tanh_f(float x) {
  x = fminf(fmaxf(x, -15.f), 15.f);
  float e = __expf(2.f * x);
  return (e - 1.f) / (e + 1.f);
}

static constexpr int SS = 256;

// ---------------- prep: pack W_ih/W_hh rows {i,g,o} to fp16, bias3 = b_ih+b_hh ----
__global__ void prep_kernel(const float* __restrict__ W_ih, const float* __restrict__ W_hh,
                            const float* __restrict__ b_ih, const float* __restrict__ b_hh,
                            __fp16* __restrict__ Wi3, __fp16* __restrict__ Wh3,
                            float* __restrict__ bias3) {
  int j3 = blockIdx.x;                 // 0..3071 packed row
  int g = j3 >> 10, j = j3 & 1023;
  int orig = (g == 0 ? 0 : (g == 1 ? 2048 : 3072)) + j;  // i,g,o rows of 4H
  int tid = threadIdx.x;
  {
    float4 v = *(const float4*)(W_hh + (size_t)orig * 1024 + tid * 4);
    f16x4 o = {(__fp16)v.x, (__fp16)v.y, (__fp16)v.z, (__fp16)v.w};
    *(f16x4*)(Wh3 + (size_t)j3 * 1024 + tid * 4) = o;
  }
  if (tid < 128) {
    float4 v = *(const float4*)(W_ih + (size_t)orig * 512 + tid * 4);
    f16x4 o = {(__fp16)v.x, (__fp16)v.y, (__fp16)v.z, (__fp16)v.w};
    *(f16x4*)(Wi3 + (size_t)j3 * 512 + tid * 4) = o;
  }
  if (tid == 0) bias3[j3] = b_ih[orig] + b_hh[orig];
}

// ---------------- gather: X[t*128+b][e] = fp16(embed[tok[b][t]][e]) ----------------
__global__ void gather_kernel(const int* __restrict__ tok, const float* __restrict__ emb,
                              __fp16* __restrict__ X) {
  int m = blockIdx.x;                  // 0..32767 = t*128 + b
  int t = m >> 7, b = m & 127;
  int tk = tok[b * SS + t];            // inputs is [B][S]
  int e0 = threadIdx.x * 8;
  const float* src = emb + (size_t)tk * 512 + e0;
  float4 v0 = *(const float4*)src;
  float4 v1 = *(const float4*)(src + 4);
  f16x8 o;
  o[0] = (__fp16)v0.x; o[1] = (__fp16)v0.y; o[2] = (__fp16)v0.z; o[3] = (__fp16)v0.w;
  o[4] = (__fp16)v1.x; o[5] = (__fp16)v1.y; o[6] = (__fp16)v1.z; o[7] = (__fp16)v1.w;
  *(f16x8*)(X + (size_t)m * 512 + e0) = o;
}

// ---------------- recurrence: persistent, fused input GEMM, direct-reg A loads ----
// 256 blocks = (bg 0..7: 16 batch rows, pinned to XCD bg via bid&7) x (n 0..31:
// 32 h-cols). 4 waves = 4 disjoint K-quarters (h: 256 K each; X: 128 K each) over
// the same 32 cols -> no duplicated A loads. Per wave register-resident B-frags:
// Wh 3g x 2ct x 8kk (192 regs) + Wi 3g x 2ct x 4kk (96 regs). Per step: issue X
// A-frags (L2/L3, pre-poll so latency hides under the wait), poll 32 per-block
// flags (relaxed agent, all waves), COMPILER barrier only (no buffer_inv!), h
// A-frags global->VGPR (XCD-L2 hit), 24 X-MFMAs + 48 h-MFMAs, 4-way K-reduce via
// padded gbuf, epilogue split over all 4 waves, per-wave vmcnt(0) drain, block
// barrier, tid0 relaxed-agent flag store.
__global__ __launch_bounds__(256, 1) void recur_kernel(const __fp16* __restrict__ Wh3,
                                                       const __fp16* __restrict__ Wi3,
                                                       const __fp16* __restrict__ X,
                                                       const float* __restrict__ bias3,
                                                       __fp16* __restrict__ hbuf,
                                                       int* __restrict__ flags,
                                                       float* __restrict__ out) {
  const int bid = blockIdx.x;
  const int bg = bid & 7, n = bid >> 3;   // XCD-local batch groups
  const int b0 = bg * 16, j0 = n * 32;
  const int tid = threadIdx.x, wid = tid >> 6, lane = tid & 63;
  const int l15 = lane & 15, quad = lane >> 4;
  const int kq = wid;                     // this wave's K-quarter
  const int ct_e = wid & 1, rh = wid >> 1;  // epilogue ownership: col-tile, row-half

  // [wave][gate][ctile][row][col+pad]; stride 20 floats -> 2-way banks (free, m136)
  __shared__ float gbuf[4][3][2][16][20];

  // persistent B fragments (col = j0 + ct*16 + l15, k = quarter + kk*32 + quad*8)
  f16x8 wh[3][2][8];
  f16x8 wi[3][2][4];
#pragma unroll
  for (int g = 0; g < 3; ++g)
#pragma unroll
    for (int ct = 0; ct < 2; ++ct) {
      const __fp16* wr = Wh3 + (size_t)(g * 1024 + j0 + ct * 16 + l15) * 1024 + kq * 256 + quad * 8;
#pragma unroll
      for (int kk = 0; kk < 8; ++kk) wh[g][ct][kk] = *(const f16x8*)(wr + kk * 32);
      const __fp16* wr2 = Wi3 + (size_t)(g * 1024 + j0 + ct * 16 + l15) * 512 + kq * 128 + quad * 8;
#pragma unroll
      for (int kk = 0; kk < 4; ++kk) wi[g][ct][kk] = *(const f16x8*)(wr2 + kk * 32);
    }

  float bs[3];
#pragma unroll
  for (int g = 0; g < 3; ++g) bs[g] = bias3[g * 1024 + j0 + ct_e * 16 + l15];

  const __fp16* xrow = X + (size_t)(b0 + l15) * 512 + kq * 128 + quad * 8;
  const __fp16* hrow = hbuf + (size_t)(b0 + l15) * 1024 + kq * 256 + quad * 8;
  int* myflag = flags + (bg * 32 + n) * 16;          // 64B apart per block
  int* pollp  = flags + (bg * 32 + (lane & 31)) * 16;

  for (int t = 0; t < SS; ++t) {
    // (a) X A-frags: no h dependency -> issue before the poll, latency hides under it
    f16x8 xa[4];
    {
      const __fp16* xp = xrow + (size_t)t * 65536;
#pragma unroll
      for (int kk = 0; kk < 4; ++kk) xa[kk] = *(const f16x8*)(xp + kk * 32);
    }
    // (b) wait for the 32 producer blocks of our batch group (relaxed polls, all
    //     waves). NO hardware fence: h lines are fresh addresses (ring buffer) so
    //     consumer L1 cannot be stale; producer vmcnt(0) ordered h into L2 before
    //     the flag. Compiler barrier stops load hoisting above the poll.
    if (t > 0) {
      for (;;) {
        int v = __hip_atomic_load(pollp, __ATOMIC_RELAXED, __HIP_MEMORY_SCOPE_AGENT);
        if (__ballot(v < t) == 0ull) break;
        __builtin_amdgcn_s_sleep(1);
      }
      asm volatile("" ::: "memory");
    }
    // (c) h A-frags straight global->VGPR (XCD L2 hit); issued before X-MFMAs so
    //     the 24 X MFMAs cover part of the load latency
    f16x8 ha[8];
    {
      const __fp16* hp = hrow + (size_t)t * 131072;
#pragma unroll
      for (int kk = 0; kk < 8; ++kk) ha[kk] = *(const f16x8*)(hp + kk * 32);
    }
    // (d) MFMA: acc starts with the fused input-GEMM contribution
    f32x4 acc[3][2];
#pragma unroll
    for (int g = 0; g < 3; ++g)
#pragma unroll
      for (int ct = 0; ct < 2; ++ct) {
        f32x4 z = {0.f, 0.f, 0.f, 0.f};
        acc[g][ct] = z;
      }
#pragma unroll
    for (int kk = 0; kk < 4; ++kk)
#pragma unroll
      for (int g = 0; g < 3; ++g)
#pragma unroll
        for (int ct = 0; ct < 2; ++ct)
          acc[g][ct] = MFMA16(xa[kk], wi[g][ct][kk], acc[g][ct]);
#pragma unroll
    for (int kk = 0; kk < 8; ++kk)
#pragma unroll
      for (int g = 0; g < 3; ++g)
#pragma unroll
        for (int ct = 0; ct < 2; ++ct)
          acc[g][ct] = MFMA16(ha[kk], wh[g][ct][kk], acc[g][ct]);
    // (e) 4-way K reduction via gbuf
#pragma unroll
    for (int g = 0; g < 3; ++g)
#pragma unroll
      for (int ct = 0; ct < 2; ++ct)
#pragma unroll
        for (int r = 0; r < 4; ++r)
          gbuf[kq][g][ct][quad * 4 + r][l15] = acc[g][ct][r];
    __syncthreads();
    float sum[3][2];
#pragma unroll
    for (int g = 0; g < 3; ++g)
#pragma unroll
      for (int rr = 0; rr < 2; ++rr) {
        const int r = rh * 2 + rr;
        sum[g][rr] = gbuf[0][g][ct_e][quad * 4 + r][l15] + gbuf[1][g][ct_e][quad * 4 + r][l15] +
                     gbuf[2][g][ct_e][quad * 4 + r][l15] + gbuf[3][g][ct_e][quad * 4 + r][l15];
      }
    __syncthreads();  // gbuf free for next step's partials
    // (f) epilogue: 2 h-values per thread, all 4 waves participate
#pragma unroll
    for (int rr = 0; rr < 2; ++rr) {
      const int r = rh * 2 + rr;
      float gi = sum[0][rr] + bs[0];
      float gg = sum[1][rr] + bs[1];
      float go = sum[2][rr] + bs[2];
      float cv = sigmoid_f(gi) * tanh_f(gg);
      float hN = sigmoid_f(go) * tanh_f(cv);
      const int row = b0 + quad * 4 + r;
      const int col = j0 + ct_e * 16 + l15;
      if (t == SS - 1) out[(size_t)row * 1024 + col] = hN;
      else hbuf[(size_t)(t + 1) * 131072 + (size_t)row * 1024 + col] = (__fp16)hN;
    }
    // (g) release: each wave drains its own stores into the XCD L2, block barrier,
    //     then ONE relaxed agent flag store per block (64B-isolated line).
    if (t < SS - 1) {
      asm volatile("s_waitcnt vmcnt(0)" ::: "memory");
      __syncthreads();
      if (tid == 0)
        __hip_atomic_store(myflag, t + 1, __ATOMIC_RELAXED, __HIP_MEMORY_SCOPE_AGENT);
    }
  }
}

extern "C" void kernel_launch(void* const* d_in, const int* in_sizes, int n_in,
                              void* d_out, int out_size, void* d_ws, size_t ws_size,
                              hipStream_t stream) {
  const int*   tok  = (const int*)d_in[0];
  const float* emb  = (const float*)d_in[1];
  const float* W_ih = (const float*)d_in[2];
  const float* W_hh = (const float*)d_in[3];
  const float* b_ih = (const float*)d_in[4];
  const float* b_hh = (const float*)d_in[5];
  float* out = (float*)d_out;
  char* ws = (char*)d_ws;

  // ws layout (bytes), total 110,129,152 (~105 MB)
  __fp16* X     = (__fp16*)(ws + 0);              // 33,554,432
  __fp16* Wi3   = (__fp16*)(ws + 33554432);       //  3,145,728
  __fp16* Wh3   = (__fp16*)(ws + 36700160);       //  6,291,456
  float*  bias3 = (float*) (ws + 42991616);       //     12,288
  int*    flags = (int*)   (ws + 43003904);       //     16,384 (256 flags, 64B apart)
  __fp16* hbuf  = (__fp16*)(ws + 43020288);       // 67,108,864 (256 step buffers)

  (void)hipMemsetAsync(flags, 0, 16384, stream);
  (void)hipMemsetAsync(hbuf, 0, 131072 * 2, stream);  // h_0 = 0

  prep_kernel<<<3072, 256, 0, stream>>>(W_ih, W_hh, b_ih, b_hh, Wi3, Wh3, bias3);
  gather_kernel<<<32768, 64, 0, stream>>>(tok, emb, X);
  recur_kernel<<<256, 256, 0, stream>>>(Wh3, Wi3, X, bias3, hbuf, flags, out);
}

// Round 4
// 1294.805 us; speedup vs baseline: 2.5244x; 1.0247x over previous
//
#include <hip/hip_runtime.h>
#include <hip/hip_fp16.h>

// Unidir_LSTM: h_t = sig(o)*tanh(sig(i)*tanh(g)); f-gate dead (cell carry always 0).
// R9: R8 failed with no counters (hang or infra). R8 had two UNPROVEN bets on the
//   spin loop: (1) inline-asm `global_load sc0` poll — if scope-01 is CU-servable,
//   the poll reads stale L1 forever -> deadlock; (2) workgroup-scope fetch_add ->
//   counter dirty in producer XCD L2, invisible to any MALL-serviced poll ->
//   deadlock if dispatch isn't perfectly XCD-pinned. Both removed.
// R9 keeps R8's levers with R7-PROVEN primitives only:
//   - ONE aggregated counter line per (group, step): producer tid0 agent-scope
//     RELAXED fetch_add at the MALL after per-wave vmcnt(0) + block barrier;
//     consumer waves poll with agent-scope RELAXED load, all 64 lanes on the SAME
//     address (one broadcast transaction per wave per iteration; 4/block vs R7's
//     128 scattered 64B-line reads), compiler barrier after.
//   - parity double-buffered gbuf -> 2 barriers/step (R7 had 3).
//   h visibility: same same-XCD-L2 bet as R5/R7 (empirically validated).
// Predict: recur 1168 -> ~800-950us, MfmaUtil ~13-15%, FETCH ~85-90MB, WRITE ~68MB,
//   conflicts 0. If "failed twice" repeats with no counters -> infra, resubmit.

typedef __fp16 f16x8 __attribute__((ext_vector_type(8)));
typedef __fp16 f16x4 __attribute__((ext_vector_type(4)));
typedef float  f32x4 __attribute__((ext_vector_type(4)));

#define MFMA16(a, b, c) __builtin_amdgcn_mfma_f32_16x16x32_f16(a, b, c, 0, 0, 0)

__device__ __forceinline__ float sigmoid_f(float x) {
  return 1.f / (1.f + __expf(-x));
}
__device__ __forceinline__ float tanh_f(float x) {
  x = fminf(fmaxf(x, -15.f), 15.f);
  float e = __expf(2.f * x);
  return (e - 1.f) / (e + 1.f);
}

static constexpr int SS = 256;

// ---------------- prep: pack W_ih/W_hh rows {i,g,o} to fp16, bias3 = b_ih+b_hh ----
__global__ void prep_kernel(const float* __restrict__ W_ih, const float* __restrict__ W_hh,
                            const float* __restrict__ b_ih, const float* __restrict__ b_hh,
                            __fp16* __restrict__ Wi3, __fp16* __restrict__ Wh3,
                            float* __restrict__ bias3) {
  int j3 = blockIdx.x;                 // 0..3071 packed row
  int g = j3 >> 10, j = j3 & 1023;
  int orig = (g == 0 ? 0 : (g == 1 ? 2048 : 3072)) + j;  // i,g,o rows of 4H
  int tid = threadIdx.x;
  {
    float4 v = *(const float4*)(W_hh + (size_t)orig * 1024 + tid * 4);
    f16x4 o = {(__fp16)v.x, (__fp16)v.y, (__fp16)v.z, (__fp16)v.w};
    *(f16x4*)(Wh3 + (size_t)j3 * 1024 + tid * 4) = o;
  }
  if (tid < 128) {
    float4 v = *(const float4*)(W_ih + (size_t)orig * 512 + tid * 4);
    f16x4 o = {(__fp16)v.x, (__fp16)v.y, (__fp16)v.z, (__fp16)v.w};
    *(f16x4*)(Wi3 + (size_t)j3 * 512 + tid * 4) = o;
  }
  if (tid == 0) bias3[j3] = b_ih[orig] + b_hh[orig];
}

// ---------------- gather: X[t*128+b][e] = fp16(embed[tok[b][t]][e]) ----------------
__global__ void gather_kernel(const int* __restrict__ tok, const float* __restrict__ emb,
                              __fp16* __restrict__ X) {
  int m = blockIdx.x;                  // 0..32767 = t*128 + b
  int t = m >> 7, b = m & 127;
  int tk = tok[b * SS + t];            // inputs is [B][S]
  int e0 = threadIdx.x * 8;
  const float* src = emb + (size_t)tk * 512 + e0;
  float4 v0 = *(const float4*)src;
  float4 v1 = *(const float4*)(src + 4);
  f16x8 o;
  o[0] = (__fp16)v0.x; o[1] = (__fp16)v0.y; o[2] = (__fp16)v0.z; o[3] = (__fp16)v0.w;
  o[4] = (__fp16)v1.x; o[5] = (__fp16)v1.y; o[6] = (__fp16)v1.z; o[7] = (__fp16)v1.w;
  *(f16x8*)(X + (size_t)m * 512 + e0) = o;
}

// ---------------- recurrence: persistent, fused input GEMM, 1-counter handoff -----
// 256 blocks = (bg 0..7: 16 batch rows, pinned to XCD bg via bid&7) x (n 0..31:
// 32 h-cols). 4 waves = 4 disjoint K-quarters. Per wave register-resident B-frags:
// Wh 3g x 2ct x 8kk + Wi 3g x 2ct x 4kk. Per step: X A-frags issued pre-poll
// (latency hides under wait), each wave polls the single (bg,t) counter (agent
// relaxed load, all lanes same addr -> 1 broadcast txn/wave), h A-frags
// global->VGPR (XCD-L2 hit), 24 X-MFMAs + 48 h-MFMAs, 4-way K-reduce via parity
// gbuf (1 barrier), epilogue on all 4 waves, per-wave vmcnt(0), block barrier,
// tid0 agent-scope fetch_add on cnt[bg][t+1] (RMW at MALL, device-visible).
__global__ __launch_bounds__(256, 1) void recur_kernel(const __fp16* __restrict__ Wh3,
                                                       const __fp16* __restrict__ Wi3,
                                                       const __fp16* __restrict__ X,
                                                       const float* __restrict__ bias3,
                                                       __fp16* __restrict__ hbuf,
                                                       int* __restrict__ cnt,
                                                       float* __restrict__ out) {
  const int bid = blockIdx.x;
  const int bg = bid & 7, n = bid >> 3;   // XCD-local batch groups
  const int b0 = bg * 16, j0 = n * 32;
  const int tid = threadIdx.x, wid = tid >> 6, lane = tid & 63;
  const int l15 = lane & 15, quad = lane >> 4;
  const int kq = wid;                     // this wave's K-quarter
  const int ct_e = wid & 1, rh = wid >> 1;  // epilogue ownership: col-tile, row-half

  // parity-double-buffered; stride 20 floats -> 2-way banks (free, m136)
  __shared__ float gbuf[2][4][3][2][16][20];

  // persistent B fragments (col = j0 + ct*16 + l15, k = quarter + kk*32 + quad*8)
  f16x8 wh[3][2][8];
  f16x8 wi[3][2][4];
#pragma unroll
  for (int g = 0; g < 3; ++g)
#pragma unroll
    for (int ct = 0; ct < 2; ++ct) {
      const __fp16* wr = Wh3 + (size_t)(g * 1024 + j0 + ct * 16 + l15) * 1024 + kq * 256 + quad * 8;
#pragma unroll
      for (int kk = 0; kk < 8; ++kk) wh[g][ct][kk] = *(const f16x8*)(wr + kk * 32);
      const __fp16* wr2 = Wi3 + (size_t)(g * 1024 + j0 + ct * 16 + l15) * 512 + kq * 128 + quad * 8;
#pragma unroll
      for (int kk = 0; kk < 4; ++kk) wi[g][ct][kk] = *(const f16x8*)(wr2 + kk * 32);
    }

  float bs[3];
#pragma unroll
  for (int g = 0; g < 3; ++g) bs[g] = bias3[g * 1024 + j0 + ct_e * 16 + l15];

  const __fp16* xrow = X + (size_t)(b0 + l15) * 512 + kq * 128 + quad * 8;
  const __fp16* hrow = hbuf + (size_t)(b0 + l15) * 1024 + kq * 256 + quad * 8;
  int* cbase = cnt + (bg << 8) * 16;      // one 64B line per (bg, t)

  for (int t = 0; t < SS; ++t) {
    // (a) X A-frags: no h dependency -> issue before the poll, latency hides under it
    f16x8 xa[4];
    {
      const __fp16* xp = xrow + (size_t)t * 65536;
#pragma unroll
      for (int kk = 0; kk < 4; ++kk) xa[kk] = *(const f16x8*)(xp + kk * 32);
    }
    // (b) wait for the 32 producer blocks of our batch group: ONE counter line,
    //     agent-scope relaxed load (device coherence point — cannot read stale),
    //     all 64 lanes on the same address = one broadcast transaction per wave.
    if (t > 0) {
      const int* pollp = cbase + t * 16;
      for (;;) {
        int v = __hip_atomic_load(pollp, __ATOMIC_RELAXED, __HIP_MEMORY_SCOPE_AGENT);
        if (v >= 32) break;
        __builtin_amdgcn_s_sleep(1);
      }
      asm volatile("" ::: "memory");
    }
    // (c) h A-frags straight global->VGPR (XCD L2 hit); issued before X-MFMAs so
    //     the 24 X MFMAs cover part of the load latency
    f16x8 ha[8];
    {
      const __fp16* hp = hrow + (size_t)t * 131072;
#pragma unroll
      for (int kk = 0; kk < 8; ++kk) ha[kk] = *(const f16x8*)(hp + kk * 32);
    }
    // (d) MFMA: acc starts with the fused input-GEMM contribution
    f32x4 acc[3][2];
#pragma unroll
    for (int g = 0; g < 3; ++g)
#pragma unroll
      for (int ct = 0; ct < 2; ++ct) {
        f32x4 z = {0.f, 0.f, 0.f, 0.f};
        acc[g][ct] = z;
      }
#pragma unroll
    for (int kk = 0; kk < 4; ++kk)
#pragma unroll
      for (int g = 0; g < 3; ++g)
#pragma unroll
        for (int ct = 0; ct < 2; ++ct)
          acc[g][ct] = MFMA16(xa[kk], wi[g][ct][kk], acc[g][ct]);
#pragma unroll
    for (int kk = 0; kk < 8; ++kk)
#pragma unroll
      for (int g = 0; g < 3; ++g)
#pragma unroll
        for (int ct = 0; ct < 2; ++ct)
          acc[g][ct] = MFMA16(ha[kk], wh[g][ct][kk], acc[g][ct]);
    // (e) 4-way K reduction via parity gbuf (single barrier; writer of parity p at
    //     t+2 is separated from readers at t by the release barrier of t+1)
    const int tp = t & 1;
#pragma unroll
    for (int g = 0; g < 3; ++g)
#pragma unroll
      for (int ct = 0; ct < 2; ++ct)
#pragma unroll
        for (int r = 0; r < 4; ++r)
          gbuf[tp][kq][g][ct][quad * 4 + r][l15] = acc[g][ct][r];
    __syncthreads();
    float sum[3][2];
#pragma unroll
    for (int g = 0; g < 3; ++g)
#pragma unroll
      for (int rr = 0; rr < 2; ++rr) {
        const int r = rh * 2 + rr;
        sum[g][rr] = gbuf[tp][0][g][ct_e][quad * 4 + r][l15] + gbuf[tp][1][g][ct_e][quad * 4 + r][l15] +
                     gbuf[tp][2][g][ct_e][quad * 4 + r][l15] + gbuf[tp][3][g][ct_e][quad * 4 + r][l15];
      }
    // (f) epilogue: 2 h-values per thread, all 4 waves participate
#pragma unroll
    for (int rr = 0; rr < 2; ++rr) {
      const int r = rh * 2 + rr;
      float gi = sum[0][rr] + bs[0];
      float gg = sum[1][rr] + bs[1];
      float go = sum[2][rr] + bs[2];
      float cv = sigmoid_f(gi) * tanh_f(gg);
      float hN = sigmoid_f(go) * tanh_f(cv);
      const int row = b0 + quad * 4 + r;
      const int col = j0 + ct_e * 16 + l15;
      if (t == SS - 1) out[(size_t)row * 1024 + col] = hN;
      else hbuf[(size_t)(t + 1) * 131072 + (size_t)row * 1024 + col] = (__fp16)hN;
    }
    // (g) release: per-wave drain into the XCD L2, block barrier, then ONE
    //     agent-scope fetch_add at the MALL (device-visible, hang-proof).
    if (t < SS - 1) {
      asm volatile("s_waitcnt vmcnt(0)" ::: "memory");
      __syncthreads();
      if (tid == 0)
        __hip_atomic_fetch_add(cbase + (t + 1) * 16, 1,
                               __ATOMIC_RELAXED, __HIP_MEMORY_SCOPE_AGENT);
    }
  }
}

extern "C" void kernel_launch(void* const* d_in, const int* in_sizes, int n_in,
                              void* d_out, int out_size, void* d_ws, size_t ws_size,
                              hipStream_t stream) {
  const int*   tok  = (const int*)d_in[0];
  const float* emb  = (const float*)d_in[1];
  const float* W_ih = (const float*)d_in[2];
  const float* W_hh = (const float*)d_in[3];
  const float* b_ih = (const float*)d_in[4];
  const float* b_hh = (const float*)d_in[5];
  float* out = (float*)d_out;
  char* ws = (char*)d_ws;

  // ws layout (bytes), total 110,243,840 (~105 MB)
  __fp16* X     = (__fp16*)(ws + 0);              // 33,554,432
  __fp16* Wi3   = (__fp16*)(ws + 33554432);       //  3,145,728
  __fp16* Wh3   = (__fp16*)(ws + 36700160);       //  6,291,456
  float*  bias3 = (float*) (ws + 42991616);       //     12,288
  int*    cnt   = (int*)   (ws + 43003904);       //    131,072 (8 groups x 256 steps, 64B lines)
  __fp16* hbuf  = (__fp16*)(ws + 43134976);       // 67,108,864 (256 step buffers)

  (void)hipMemsetAsync(cnt, 0, 131072, stream);
  (void)hipMemsetAsync(hbuf, 0, 131072 * 2, stream);  // h_0 = 0

  prep_kernel<<<3072, 256, 0, stream>>>(W_ih, W_hh, b_ih, b_hh, Wi3, Wh3, bias3);
  gather_kernel<<<32768, 64, 0, stream>>>(tok, emb, X);
  recur_kernel<<<256, 256, 0, stream>>>(Wh3, Wi3, X, bias3, hbuf, cnt, out);
}